// Round 1
// baseline (320.010 us; speedup 1.0000x reference)
//
#include <hip/hip_runtime.h>
#include <hip/hip_bf16.h>

typedef __attribute__((ext_vector_type(8))) short short8;
typedef __attribute__((ext_vector_type(4))) float f32x4;

struct alignas(16) US8 { unsigned short s[8]; };

// ---------------- ndtri in double (Acklam + 2 Halley refinements) ----------------
__device__ double ndtri_d(double p) {
    const double a1 = -3.969683028665376e+01, a2 = 2.209460984245205e+02,
                 a3 = -2.759285104469687e+02, a4 = 1.383577518672690e+02,
                 a5 = -3.066479806614716e+01, a6 = 2.506628277459239e+00;
    const double b1 = -5.447609879822406e+01, b2 = 1.615858368580409e+02,
                 b3 = -1.556989798598866e+02, b4 = 6.680131188771972e+01,
                 b5 = -1.328068155288572e+01;
    const double c1 = -7.784894002430293e-03, c2 = -3.223964580411365e-01,
                 c3 = -2.400758277161838e+00, c4 = -2.549732539343734e+00,
                 c5 = 4.374664141464968e+00,  c6 = 2.938163982698783e+00;
    const double d1 = 7.784695709041462e-03, d2 = 3.224671290700398e-01,
                 d3 = 2.445134137142996e+00, d4 = 3.754408661907416e+00;
    const double plow = 0.02425, phigh = 1.0 - 0.02425;
    double x;
    if (p < plow) {
        double q = sqrt(-2.0 * log(p));
        x = (((((c1*q+c2)*q+c3)*q+c4)*q+c5)*q+c6) / ((((d1*q+d2)*q+d3)*q+d4)*q+1.0);
    } else if (p <= phigh) {
        double q = p - 0.5, r = q * q;
        x = (((((a1*r+a2)*r+a3)*r+a4)*r+a5)*r+a6)*q / (((((b1*r+b2)*r+b3)*r+b4)*r+b5)*r+1.0);
    } else {
        double q = sqrt(-2.0 * log(1.0 - p));
        x = -(((((c1*q+c2)*q+c3)*q+c4)*q+c5)*q+c6) / ((((d1*q+d2)*q+d3)*q+d4)*q+1.0);
    }
    #pragma unroll
    for (int it = 0; it < 2; ++it) {
        double e = 0.5 * erfc(-x * 0.70710678118654752440) - p;
        double u = e * 2.50662827463100050242 * exp(0.5 * x * x);
        x = x - u / (1.0 + 0.5 * x * u);
    }
    return x;
}

// table[32], bounds[32] (bounds[31]=+inf), lut[256] bucket->base index
__global__ void build_table_k(float* __restrict__ table, float* __restrict__ bounds,
                              unsigned char* __restrict__ lut) {
    __shared__ float sT[32], sBd[32];
    const int i = threadIdx.x;  // 0..31
    const double OFF = 0.9677083;
    double v;
    if (i == 16) {
        v = 0.0;
    } else if (i < 16) {
        const double a = 1.0 - OFF;
        double p = a + (0.5 - a) * ((double)i / 16.0);
        v = ndtri_d(p) / (-ndtri_d(a));
    } else {
        int j = i - 16;
        double p = 0.5 + (OFF - 0.5) * ((double)j / 15.0);
        v = ndtri_d(p) / ndtri_d(OFF);
    }
    float tv = (float)v;
    sT[i] = tv;
    table[i] = tv;
    __syncthreads();
    float bd;
    if (i < 31) bd = 0.5f * (sT[i] + sT[i + 1]);   // fp32, like reference
    else        bd = __builtin_inff();
    sBd[i] = bd;
    bounds[i] = bd;
    __syncthreads();
    // LUT with margin 2^-20: base[j] = count(bounds < n_j - margin).
    for (int j = i; j < 256; j += 32) {
        float nj = (float)j * (1.0f / 128.0f) - 1.0f - 0x1p-20f;
        int c = 0;
        #pragma unroll
        for (int k = 0; k < 31; ++k) c += (sBd[k] < nj) ? 1 : 0;
        lut[j] = (unsigned char)c;
    }
}

// ---------------- blockwise NF5 quantize: fp32 -> bf16 ----------------
__device__ __forceinline__ unsigned short q_one(float n, float scale,
                                                const float* sT, const float* sBnd,
                                                const unsigned char* sLut) {
    float u = fmaf(n, 0.5f, 0.5f);                 // [0,1]
    int b = (int)(u * 256.0f);
    b = min(b, 255);
    int base = sLut[b];
    int idx = base + ((sBnd[base] < n) ? 1 : 0);   // == count(bounds < n)
    float q = sT[idx] * scale;                     // exact fp32 (pow2 scale)
    __hip_bfloat16 h = __float2bfloat16(q);
    return *reinterpret_cast<unsigned short*>(&h);
}

__global__ __launch_bounds__(256) void quantize_k(const float4* __restrict__ x,
                                                  US8* __restrict__ qx, int nblk_x, int n8x,
                                                  const float4* __restrict__ wgt,
                                                  US8* __restrict__ qw, int n8w,
                                                  const float* __restrict__ table,
                                                  const float* __restrict__ bounds,
                                                  const unsigned char* __restrict__ lut) {
    __shared__ float sT[32], sBnd[32];
    __shared__ unsigned char sLut[256];
    const int tid = threadIdx.x;
    if (tid < 32) { sT[tid] = table[tid]; sBnd[tid] = bounds[tid]; }
    sLut[tid] = lut[tid];
    __syncthreads();
    const float4* in; US8* out; int t, n8;
    if ((int)blockIdx.x < nblk_x) { in = x;   out = qx; t = blockIdx.x * 256 + tid;            n8 = n8x; }
    else                          { in = wgt; out = qw; t = (blockIdx.x - nblk_x) * 256 + tid; n8 = n8w; }
    if (t >= n8) return;
    float4 v0 = in[2 * t];
    float4 v1 = in[2 * t + 1];
    float am = fmaxf(fmaxf(fmaxf(fabsf(v0.x), fabsf(v0.y)), fmaxf(fabsf(v0.z), fabsf(v0.w))),
                     fmaxf(fmaxf(fabsf(v1.x), fabsf(v1.y)), fmaxf(fabsf(v1.z), fabsf(v1.w))));
    am = fmaxf(am, __shfl_xor(am, 1));
    am = fmaxf(am, __shfl_xor(am, 2));
    am = fmaxf(am, 1e-12f);
    int e;
    float m = frexpf(am, &e);                      // am = m * 2^e, m in [0.5,1)
    int se = (m == 0.5f) ? (e - 1) : e;
    float scale = ldexpf(1.0f, se);
    float inv   = ldexpf(1.0f, -se);               // exact reciprocal
    US8 o;
    o.s[0] = q_one(v0.x * inv, scale, sT, sBnd, sLut);
    o.s[1] = q_one(v0.y * inv, scale, sT, sBnd, sLut);
    o.s[2] = q_one(v0.z * inv, scale, sT, sBnd, sLut);
    o.s[3] = q_one(v0.w * inv, scale, sT, sBnd, sLut);
    o.s[4] = q_one(v1.x * inv, scale, sT, sBnd, sLut);
    o.s[5] = q_one(v1.y * inv, scale, sT, sBnd, sLut);
    o.s[6] = q_one(v1.z * inv, scale, sT, sBnd, sLut);
    o.s[7] = q_one(v1.w * inv, scale, sT, sBnd, sLut);
    out[t] = o;
}

// ---------------- bf16 MFMA GEMM, 256x256 tile, 8 waves, phase-split pipeline ----
// C[M,N] = A[M,K] * B[N,K]^T + bias.
// LDS layout (per 64-k tile, per matrix): 32 chunks of [8 rows][8 octets], with the
// verified XOR swizzle: within a chunk, 16B slot (r8,u) holds k-octet u^r8 of row r8.
// gload_lds writes lane l at slot l -> (r8=l>>3, u=l&7); global source octet (l&7)^(l>>3).
// Fragment read for row r, octet k8: slot u = k8 ^ (r&7)  -> conflict-free (measured 0).
//
// Schedule: 4 C-quadrant phases per K-tile (full K=64 per phase), 2-slot LDS dbuf,
// staging split into 4 groups ordered by first consumption:
//   A1 = A rows {0-63,128-191}   (read at phase mq=0)
//   B1 = B rows {q*64 .. q*64+31} (read at phase nq=0)
//   B2 = B rows {q*64+32 .. +63}  (read at phase nq=1)
//   A2 = A rows {64-127,192-255}  (read at phase mq=1)
// Per-wave vmcnt ledger (units = gloads, 2 per group), steady state:
//   enter W_a: {A1,B1,B2,A2}(t)=8 -> vmcnt(4) completes A1,B1
//   P1 issues A1(t+1) -> 6;  W_b vmcnt(4) completes B2(t)
//   P2 issues B1(t+1) -> 6;  W_c vmcnt(4) completes A2(t)
//   P3 issues B2(t+1); P4 issues A2(t+1) -> 8.  Never drains to 0 in main loop.
// Final tile peeled: waits 4 -> 2 -> 0 (epilogue drain).
__device__ __forceinline__ void gload_lds16(const unsigned short* g, unsigned short* s) {
    __builtin_amdgcn_global_load_lds(
        (const __attribute__((address_space(1))) unsigned int*)g,
        (__attribute__((address_space(3))) unsigned int*)s, 16, 0, 0);
}

#define STAGE2(G0, C0, G1, C1, SM, T1)                                       \
    { const int sl_ = (T1) & 1;                                              \
      gload_lds16((G0) + (size_t)(T1) * 64, &SM[sl_][(C0) * 512]);           \
      gload_lds16((G1) + (size_t)(T1) * 64, &SM[sl_][(C1) * 512]); }

// One phase: 12 ds_read_b128 + stage 1 group + 16 MFMA (setprio-wrapped).
// MQ/NQ must be literals so acc indexing stays compile-time (no scratch).
#define PHASE(MQ, NQ, SLOT, STAGE)                                           \
    {                                                                        \
        short8 a_[2][4], b_[2][2];                                           \
        _Pragma("unroll")                                                    \
        for (int ks = 0; ks < 2; ++ks) {                                     \
            const int k8_ = ks * 4 + quad;                                   \
            _Pragma("unroll")                                                \
            for (int i = 0; i < 4; ++i) {                                    \
                const int ra = wm + (MQ) * 64 + i * 16 + rsel;               \
                a_[ks][i] = *(const short8*)&sA[SLOT][                       \
                    ((ra >> 3) * 64 + (ra & 7) * 8 + ((k8_ ^ ra) & 7)) * 8]; \
            }                                                                \
            _Pragma("unroll")                                                \
            for (int j = 0; j < 2; ++j) {                                    \
                const int rb = wn + (NQ) * 32 + j * 16 + rsel;               \
                b_[ks][j] = *(const short8*)&sB[SLOT][                       \
                    ((rb >> 3) * 64 + (rb & 7) * 8 + ((k8_ ^ rb) & 7)) * 8]; \
            }                                                                \
        }                                                                    \
        STAGE;                                                               \
        __builtin_amdgcn_s_setprio(1);                                       \
        _Pragma("unroll")                                                    \
        for (int ks = 0; ks < 2; ++ks)                                       \
            _Pragma("unroll")                                                \
            for (int i = 0; i < 4; ++i)                                      \
                _Pragma("unroll")                                            \
                for (int j = 0; j < 2; ++j)                                  \
                    acc[(MQ) * 4 + i][(NQ) * 2 + j] =                        \
                        __builtin_amdgcn_mfma_f32_16x16x32_bf16(             \
                            a_[ks][i], b_[ks][j],                            \
                            acc[(MQ) * 4 + i][(NQ) * 2 + j], 0, 0, 0);       \
        __builtin_amdgcn_s_setprio(0);                                       \
    }

__global__ __launch_bounds__(512, 1) void gemm_bt_k(const unsigned short* __restrict__ A,
                                                    const unsigned short* __restrict__ B,
                                                    const float* __restrict__ bias,
                                                    float* __restrict__ C,
                                                    int M, int N, int K) {
    __shared__ unsigned short sA[2][256 * 64];   // 64 KiB
    __shared__ unsigned short sB[2][256 * 64];   // 64 KiB
    const int t = threadIdx.x;
    const int w = t >> 6, l = t & 63;

    // XCD-aware swizzle: contiguous gid chunk per XCD; n fastest so the A-panel
    // (512 KB) is reused across the 4 n-blocks via L2; B (2 MB total) L2-resident.
    const int nB = N >> 8, mB = M >> 8;
    int m_idx, n_idx;
    {
        const unsigned int lin = blockIdx.x;
        const unsigned int nwg = (unsigned int)(nB * mB);
        unsigned int gid = lin;
        if ((nwg & 7u) == 0u) {
            const unsigned int per = nwg >> 3;
            gid = (lin & 7u) * per + (lin >> 3);
        }
        n_idx = (int)(gid % (unsigned int)nB);
        m_idx = (int)(gid / (unsigned int)nB);
    }
    const int m_blk = m_idx << 8, n_blk = n_idx << 8;
    const int wm = (w >> 2) * 128;          // wave A-row base (2 waves in M)
    const int wn = (w & 3) * 64;            // wave B-row base (4 waves in N)
    const int rsel = l & 15, quad = l >> 4;

    // ---- staging geometry (per wave: 2 chunks per group) ----
    const int st_row = l >> 3;
    const int st_oct = (l & 7) ^ st_row;
    const int ja0 = 2 * w, ja1 = 2 * w + 1;
    const int cA1_0 = (ja0 < 8) ? ja0 : ja0 + 8;          // A1: chunks {0-7,16-23}
    const int cA1_1 = (ja1 < 8) ? ja1 : ja1 + 8;
    const int cA2_0 = cA1_0 + 8, cA2_1 = cA1_1 + 8;       // A2: chunks {8-15,24-31}
    const int cB1_0 = (ja0 & 3) + (ja0 >> 2) * 8;         // B1: chunks {0-3,8-11,16-19,24-27}
    const int cB1_1 = (ja1 & 3) + (ja1 >> 2) * 8;
    const int cB2_0 = cB1_0 + 4, cB2_1 = cB1_1 + 4;       // B2: +4

    const unsigned short* gA1_0 = A + (size_t)(m_blk + cA1_0 * 8 + st_row) * K + st_oct * 8;
    const unsigned short* gA1_1 = A + (size_t)(m_blk + cA1_1 * 8 + st_row) * K + st_oct * 8;
    const unsigned short* gA2_0 = A + (size_t)(m_blk + cA2_0 * 8 + st_row) * K + st_oct * 8;
    const unsigned short* gA2_1 = A + (size_t)(m_blk + cA2_1 * 8 + st_row) * K + st_oct * 8;
    const unsigned short* gB1_0 = B + (size_t)(n_blk + cB1_0 * 8 + st_row) * K + st_oct * 8;
    const unsigned short* gB1_1 = B + (size_t)(n_blk + cB1_1 * 8 + st_row) * K + st_oct * 8;
    const unsigned short* gB2_0 = B + (size_t)(n_blk + cB2_0 * 8 + st_row) * K + st_oct * 8;
    const unsigned short* gB2_1 = B + (size_t)(n_blk + cB2_1 * 8 + st_row) * K + st_oct * 8;

    f32x4 acc[8][4];
    #pragma unroll
    for (int i = 0; i < 8; ++i)
        #pragma unroll
        for (int j = 0; j < 4; ++j)
            acc[i][j] = (f32x4){0.f, 0.f, 0.f, 0.f};

    // ---- prologue: stage tile 0 in group order A1, B1, B2, A2 ----
    STAGE2(gA1_0, cA1_0, gA1_1, cA1_1, sA, 0);
    STAGE2(gB1_0, cB1_0, gB1_1, cB1_1, sB, 0);
    STAGE2(gB2_0, cB2_0, gB2_1, cB2_1, sB, 0);
    STAGE2(gA2_0, cA2_0, gA2_1, cA2_1, sA, 0);

    const int nt = K >> 6;
    for (int tt = 0; tt < nt - 1; ++tt) {
        const int sl = tt & 1;
        asm volatile("s_waitcnt vmcnt(4)" ::: "memory");   // A1,B1(tt) complete
        __builtin_amdgcn_s_barrier();
        PHASE(0, 0, sl, STAGE2(gA1_0, cA1_0, gA1_1, cA1_1, sA, tt + 1));
        asm volatile("s_waitcnt vmcnt(4)" ::: "memory");   // B2(tt) complete
        __builtin_amdgcn_s_barrier();
        PHASE(0, 1, sl, STAGE2(gB1_0, cB1_0, gB1_1, cB1_1, sB, tt + 1));
        asm volatile("s_waitcnt vmcnt(4)" ::: "memory");   // A2(tt) complete
        __builtin_amdgcn_s_barrier();
        PHASE(1, 0, sl, STAGE2(gB2_0, cB2_0, gB2_1, cB2_1, sB, tt + 1));
        __builtin_amdgcn_s_barrier();
        PHASE(1, 1, sl, STAGE2(gA2_0, cA2_0, gA2_1, cA2_1, sA, tt + 1));
    }
    {   // ---- final tile (no staging): drain 4 -> 2 -> 0 ----
        const int sl = (nt - 1) & 1;
        asm volatile("s_waitcnt vmcnt(4)" ::: "memory");
        __builtin_amdgcn_s_barrier();
        PHASE(0, 0, sl, ((void)0));
        asm volatile("s_waitcnt vmcnt(2)" ::: "memory");
        __builtin_amdgcn_s_barrier();
        PHASE(0, 1, sl, ((void)0));
        asm volatile("s_waitcnt vmcnt(0)" ::: "memory");
        __builtin_amdgcn_s_barrier();
        PHASE(1, 0, sl, ((void)0));
        __builtin_amdgcn_s_barrier();
        PHASE(1, 1, sl, ((void)0));
    }

    // ---- epilogue: C/D layout col = l&15, row = (l>>4)*4 + r ----
    float bv[4];
    #pragma unroll
    for (int jj = 0; jj < 4; ++jj) bv[jj] = bias[n_blk + wn + jj * 16 + rsel];
    #pragma unroll
    for (int ii = 0; ii < 8; ++ii) {
        const int rbase = m_blk + wm + (ii >> 2) * 64 + (ii & 3) * 16 + quad * 4;
        #pragma unroll
        for (int r = 0; r < 4; ++r) {
            float* cp = C + (size_t)(rbase + r) * N + n_blk + wn + rsel;
            #pragma unroll
            for (int jj = 0; jj < 4; ++jj)
                cp[jj * 16] = acc[ii][jj][r] + bv[jj];
        }
    }
}

extern "C" void kernel_launch(void* const* d_in, const int* in_sizes, int n_in,
                              void* d_out, int out_size, void* d_ws, size_t ws_size,
                              hipStream_t stream) {
    const float* x    = (const float*)d_in[0];
    const float* wgt  = (const float*)d_in[1];
    const float* bias = (const float*)d_in[2];
    float* out = (float*)d_out;

    const int x_size = in_sizes[0];      // 33554432
    const int w_size = in_sizes[1];      // 1048576
    const int N = in_sizes[2];           // 1024 (Dout)
    const int K = w_size / N;            // 1024 (Din)
    const int M = x_size / K;            // 32768

    char* ws = (char*)d_ws;
    unsigned short* qx = (unsigned short*)ws;
    unsigned short* qw = (unsigned short*)(ws + (size_t)M * K * sizeof(unsigned short));
    float* table  = (float*)(ws + (size_t)M * K * 2 + (size_t)N * K * 2);
    float* bounds = table + 32;
    unsigned char* lut = (unsigned char*)(bounds + 32);

    build_table_k<<<1, 32, 0, stream>>>(table, bounds, lut);

    const int n8x = x_size / 8, n8w = w_size / 8;
    const int nblk_x = (n8x + 255) / 256, nblk_w = (n8w + 255) / 256;
    quantize_k<<<nblk_x + nblk_w, 256, 0, stream>>>(
        (const float4*)x, (US8*)qx, nblk_x, n8x,
        (const float4*)wgt, (US8*)qw, n8w, table, bounds, lut);

    const int grid = (M / 256) * (N / 256);   // 512
    gemm_bt_k<<<grid, 512, 0, stream>>>(qx, qw, bias, out, M, N, K);
}

// Round 2
// 304.872 us; speedup vs baseline: 1.0497x; 1.0497x over previous
//
#include <hip/hip_runtime.h>
#include <hip/hip_bf16.h>

typedef __attribute__((ext_vector_type(8))) short short8;
typedef __attribute__((ext_vector_type(4))) float f32x4;

struct alignas(16) US8 { unsigned short s[8]; };

// ---------------- ndtri in double (Acklam + 2 Halley refinements) ----------------
__device__ double ndtri_d(double p) {
    const double a1 = -3.969683028665376e+01, a2 = 2.209460984245205e+02,
                 a3 = -2.759285104469687e+02, a4 = 1.383577518672690e+02,
                 a5 = -3.066479806614716e+01, a6 = 2.506628277459239e+00;
    const double b1 = -5.447609879822406e+01, b2 = 1.615858368580409e+02,
                 b3 = -1.556989798598866e+02, b4 = 6.680131188771972e+01,
                 b5 = -1.328068155288572e+01;
    const double c1 = -7.784894002430293e-03, c2 = -3.223964580411365e-01,
                 c3 = -2.400758277161838e+00, c4 = -2.549732539343734e+00,
                 c5 = 4.374664141464968e+00,  c6 = 2.938163982698783e+00;
    const double d1 = 7.784695709041462e-03, d2 = 3.224671290700398e-01,
                 d3 = 2.445134137142996e+00, d4 = 3.754408661907416e+00;
    const double plow = 0.02425, phigh = 1.0 - 0.02425;
    double x;
    if (p < plow) {
        double q = sqrt(-2.0 * log(p));
        x = (((((c1*q+c2)*q+c3)*q+c4)*q+c5)*q+c6) / ((((d1*q+d2)*q+d3)*q+d4)*q+1.0);
    } else if (p <= phigh) {
        double q = p - 0.5, r = q * q;
        x = (((((a1*r+a2)*r+a3)*r+a4)*r+a5)*r+a6)*q / (((((b1*r+b2)*r+b3)*r+b4)*r+b5)*r+1.0);
    } else {
        double q = sqrt(-2.0 * log(1.0 - p));
        x = -(((((c1*q+c2)*q+c3)*q+c4)*q+c5)*q+c6) / ((((d1*q+d2)*q+d3)*q+d4)*q+1.0);
    }
    #pragma unroll
    for (int it = 0; it < 2; ++it) {
        double e = 0.5 * erfc(-x * 0.70710678118654752440) - p;
        double u = e * 2.50662827463100050242 * exp(0.5 * x * x);
        x = x - u / (1.0 + 0.5 * x * u);
    }
    return x;
}

// table[32], bounds[32] (bounds[31]=+inf), lut[256] bucket->base index
__global__ void build_table_k(float* __restrict__ table, float* __restrict__ bounds,
                              unsigned char* __restrict__ lut) {
    __shared__ float sT[32], sBd[32];
    const int i = threadIdx.x;  // 0..31
    const double OFF = 0.9677083;
    double v;
    if (i == 16) {
        v = 0.0;
    } else if (i < 16) {
        const double a = 1.0 - OFF;
        double p = a + (0.5 - a) * ((double)i / 16.0);
        v = ndtri_d(p) / (-ndtri_d(a));
    } else {
        int j = i - 16;
        double p = 0.5 + (OFF - 0.5) * ((double)j / 15.0);
        v = ndtri_d(p) / ndtri_d(OFF);
    }
    float tv = (float)v;
    sT[i] = tv;
    table[i] = tv;
    __syncthreads();
    float bd;
    if (i < 31) bd = 0.5f * (sT[i] + sT[i + 1]);   // fp32, like reference
    else        bd = __builtin_inff();
    sBd[i] = bd;
    bounds[i] = bd;
    __syncthreads();
    // LUT with margin 2^-20: base[j] = count(bounds < n_j - margin).
    for (int j = i; j < 256; j += 32) {
        float nj = (float)j * (1.0f / 128.0f) - 1.0f - 0x1p-20f;
        int c = 0;
        #pragma unroll
        for (int k = 0; k < 31; ++k) c += (sBd[k] < nj) ? 1 : 0;
        lut[j] = (unsigned char)c;
    }
}

// ---------------- blockwise NF5 quantize: fp32 -> bf16 ----------------
__device__ __forceinline__ unsigned short q_one(float n, float scale,
                                                const float* sT, const float* sBnd,
                                                const unsigned char* sLut) {
    float u = fmaf(n, 0.5f, 0.5f);                 // [0,1]
    int b = (int)(u * 256.0f);
    b = min(b, 255);
    int base = sLut[b];
    int idx = base + ((sBnd[base] < n) ? 1 : 0);   // == count(bounds < n)
    float q = sT[idx] * scale;                     // exact fp32 (pow2 scale)
    __hip_bfloat16 h = __float2bfloat16(q);
    return *reinterpret_cast<unsigned short*>(&h);
}

__global__ __launch_bounds__(256) void quantize_k(const float4* __restrict__ x,
                                                  US8* __restrict__ qx, int nblk_x, int n8x,
                                                  const float4* __restrict__ wgt,
                                                  US8* __restrict__ qw, int n8w,
                                                  const float* __restrict__ table,
                                                  const float* __restrict__ bounds,
                                                  const unsigned char* __restrict__ lut) {
    __shared__ float sT[32], sBnd[32];
    __shared__ unsigned char sLut[256];
    const int tid = threadIdx.x;
    if (tid < 32) { sT[tid] = table[tid]; sBnd[tid] = bounds[tid]; }
    sLut[tid] = lut[tid];
    __syncthreads();
    const float4* in; US8* out; int t, n8;
    if ((int)blockIdx.x < nblk_x) { in = x;   out = qx; t = blockIdx.x * 256 + tid;            n8 = n8x; }
    else                          { in = wgt; out = qw; t = (blockIdx.x - nblk_x) * 256 + tid; n8 = n8w; }
    if (t >= n8) return;
    float4 v0 = in[2 * t];
    float4 v1 = in[2 * t + 1];
    float am = fmaxf(fmaxf(fmaxf(fabsf(v0.x), fabsf(v0.y)), fmaxf(fabsf(v0.z), fabsf(v0.w))),
                     fmaxf(fmaxf(fabsf(v1.x), fabsf(v1.y)), fmaxf(fabsf(v1.z), fabsf(v1.w))));
    am = fmaxf(am, __shfl_xor(am, 1));
    am = fmaxf(am, __shfl_xor(am, 2));
    am = fmaxf(am, 1e-12f);
    int e;
    float m = frexpf(am, &e);                      // am = m * 2^e, m in [0.5,1)
    int se = (m == 0.5f) ? (e - 1) : e;
    float scale = ldexpf(1.0f, se);
    float inv   = ldexpf(1.0f, -se);               // exact reciprocal
    US8 o;
    o.s[0] = q_one(v0.x * inv, scale, sT, sBnd, sLut);
    o.s[1] = q_one(v0.y * inv, scale, sT, sBnd, sLut);
    o.s[2] = q_one(v0.z * inv, scale, sT, sBnd, sLut);
    o.s[3] = q_one(v0.w * inv, scale, sT, sBnd, sLut);
    o.s[4] = q_one(v1.x * inv, scale, sT, sBnd, sLut);
    o.s[5] = q_one(v1.y * inv, scale, sT, sBnd, sLut);
    o.s[6] = q_one(v1.z * inv, scale, sT, sBnd, sLut);
    o.s[7] = q_one(v1.w * inv, scale, sT, sBnd, sLut);
    out[t] = o;
}

// ---------------- bf16 MFMA GEMM, 256x256 tile, 8 waves, phase-split pipeline ----
// C[M,N] = A[M,K] * B[N,K]^T + bias.
// LDS layout (per 64-k tile, per matrix): 32 chunks of [8 rows][8 octets], XOR swizzle:
// within a chunk, 16B slot (r8,u) holds k-octet u^r8 of row r8. gload_lds writes lane l
// at slot l; global source octet (l&7)^(l>>3). Fragment read at fixed k8 hits all 8
// bank-quads across r8 -> conflict-free (measured 0).
//
// Snake-order phases with register-resident fragments (unique LDS traffic only:
// 24 ds_read_b128 / wave / K-tile instead of 48):
//   P1: read A[mq0](8) + B[nq0](4) ; MFMA mq0 x nq0 ; stage A1(t+1)
//   P2: read B[nq1](4)             ; MFMA mq0 x nq1 ; stage B1(t+1)   (A regs reused)
//   P3: read A[mq1](8, overwrite)  ; MFMA mq1 x nq1 ; stage B2(t+1)   (B1 regs reused)
//   P4: no reads, NO barrier       ; MFMA mq1 x nq0 ; stage A2(t+1)   (both reused)
// Staging groups (issue order == consumption order):
//   A1 = A rows {0-63,128-191}, B1 = B rows {wn..wn+31}, B2 = {wn+32..+63},
//   A2 = A rows {64-127,192-255}
// Per-wave vmcnt ledger (2 gloads per group), steady state 8 outstanding:
//   P1 vmcnt(4) completes A1,B1(t); P2 vmcnt(4) completes B2(t);
//   P3 vmcnt(4) completes A2(t); never drains to 0 in main loop.
// Final tile peeled: waits 4 -> 2 -> 0.
__device__ __forceinline__ void gload_lds16(const unsigned short* g, unsigned short* s) {
    __builtin_amdgcn_global_load_lds(
        (const __attribute__((address_space(1))) unsigned int*)g,
        (__attribute__((address_space(3))) unsigned int*)s, 16, 0, 0);
}

#define STAGE2(G0, C0, G1, C1, SM, T1)                                       \
    { const int sl_ = (T1) & 1;                                              \
      gload_lds16((G0) + (size_t)(T1) * 64, &SM[sl_][(C0) * 512]);           \
      gload_lds16((G1) + (size_t)(T1) * 64, &SM[sl_][(C1) * 512]); }

// Fragment loads: compile-time register indices, runtime LDS addresses.
#define READ_A(DST, MQ, SLOT)                                                \
    _Pragma("unroll")                                                        \
    for (int ks = 0; ks < 2; ++ks) {                                         \
        const int k8_ = ks * 4 + quad;                                       \
        _Pragma("unroll")                                                    \
        for (int i = 0; i < 4; ++i) {                                        \
            const int ra = wm + (MQ) * 64 + i * 16 + rsel;                   \
            DST[ks][i] = *(const short8*)&sA[SLOT][                          \
                ((ra >> 3) * 64 + (ra & 7) * 8 + ((k8_ ^ ra) & 7)) * 8];     \
        }                                                                    \
    }

#define READ_B(DST, NQ, SLOT)                                                \
    _Pragma("unroll")                                                        \
    for (int ks = 0; ks < 2; ++ks) {                                         \
        const int k8_ = ks * 4 + quad;                                       \
        _Pragma("unroll")                                                    \
        for (int j = 0; j < 2; ++j) {                                        \
            const int rb = wn + (NQ) * 32 + j * 16 + rsel;                   \
            DST[ks][j] = *(const short8*)&sB[SLOT][                          \
                ((rb >> 3) * 64 + (rb & 7) * 8 + ((k8_ ^ rb) & 7)) * 8];     \
        }                                                                    \
    }

#define MFMA16(AF, BF, IOFF, JOFF)                                           \
    __builtin_amdgcn_s_setprio(1);                                           \
    _Pragma("unroll")                                                        \
    for (int ks = 0; ks < 2; ++ks)                                           \
        _Pragma("unroll")                                                    \
        for (int i = 0; i < 4; ++i)                                          \
            _Pragma("unroll")                                                \
            for (int j = 0; j < 2; ++j)                                      \
                acc[(IOFF) + i][(JOFF) + j] =                                \
                    __builtin_amdgcn_mfma_f32_16x16x32_bf16(                 \
                        AF[ks][i], BF[ks][j],                                \
                        acc[(IOFF) + i][(JOFF) + j], 0, 0, 0);               \
    __builtin_amdgcn_s_setprio(0);

#define VMW(N) asm volatile("s_waitcnt vmcnt(" #N ")" ::: "memory")

__global__ __launch_bounds__(512, 1) void gemm_bt_k(const unsigned short* __restrict__ A,
                                                    const unsigned short* __restrict__ B,
                                                    const float* __restrict__ bias,
                                                    float* __restrict__ C,
                                                    int M, int N, int K) {
    __shared__ unsigned short sA[2][256 * 64];   // 64 KiB
    __shared__ unsigned short sB[2][256 * 64];   // 64 KiB
    const int t = threadIdx.x;
    const int w = t >> 6, l = t & 63;

    // XCD-aware swizzle: contiguous gid chunk per XCD, n fastest (A-panel L2 reuse).
    const int nB = N >> 8, mB = M >> 8;
    int m_idx, n_idx;
    {
        const unsigned int lin = blockIdx.x;
        const unsigned int nwg = (unsigned int)(nB * mB);
        unsigned int gid = lin;
        if ((nwg & 7u) == 0u) {
            const unsigned int per = nwg >> 3;
            gid = (lin & 7u) * per + (lin >> 3);
        }
        n_idx = (int)(gid % (unsigned int)nB);
        m_idx = (int)(gid / (unsigned int)nB);
    }
    const int m_blk = m_idx << 8, n_blk = n_idx << 8;
    const int wm = (w >> 2) * 128;          // wave A-row base (2 waves in M)
    const int wn = (w & 3) * 64;            // wave B-row base (4 waves in N)
    const int rsel = l & 15, quad = l >> 4;

    // ---- staging geometry (per wave: 2 chunks per group) ----
    const int st_row = l >> 3;
    const int st_oct = (l & 7) ^ st_row;
    const int ja0 = 2 * w, ja1 = 2 * w + 1;
    const int cA1_0 = (ja0 < 8) ? ja0 : ja0 + 8;          // A1: chunks {0-7,16-23}
    const int cA1_1 = (ja1 < 8) ? ja1 : ja1 + 8;
    const int cA2_0 = cA1_0 + 8, cA2_1 = cA1_1 + 8;       // A2: chunks {8-15,24-31}
    const int cB1_0 = (ja0 & 3) + (ja0 >> 2) * 8;         // B1: chunks {0-3,8-11,16-19,24-27}
    const int cB1_1 = (ja1 & 3) + (ja1 >> 2) * 8;
    const int cB2_0 = cB1_0 + 4, cB2_1 = cB1_1 + 4;       // B2: +4

    const unsigned short* gA1_0 = A + (size_t)(m_blk + cA1_0 * 8 + st_row) * K + st_oct * 8;
    const unsigned short* gA1_1 = A + (size_t)(m_blk + cA1_1 * 8 + st_row) * K + st_oct * 8;
    const unsigned short* gA2_0 = A + (size_t)(m_blk + cA2_0 * 8 + st_row) * K + st_oct * 8;
    const unsigned short* gA2_1 = A + (size_t)(m_blk + cA2_1 * 8 + st_row) * K + st_oct * 8;
    const unsigned short* gB1_0 = B + (size_t)(n_blk + cB1_0 * 8 + st_row) * K + st_oct * 8;
    const unsigned short* gB1_1 = B + (size_t)(n_blk + cB1_1 * 8 + st_row) * K + st_oct * 8;
    const unsigned short* gB2_0 = B + (size_t)(n_blk + cB2_0 * 8 + st_row) * K + st_oct * 8;
    const unsigned short* gB2_1 = B + (size_t)(n_blk + cB2_1 * 8 + st_row) * K + st_oct * 8;

    f32x4 acc[8][4];
    #pragma unroll
    for (int i = 0; i < 8; ++i)
        #pragma unroll
        for (int j = 0; j < 4; ++j)
            acc[i][j] = (f32x4){0.f, 0.f, 0.f, 0.f};

    // ---- prologue: stage tile 0 in group order A1, B1, B2, A2 ----
    STAGE2(gA1_0, cA1_0, gA1_1, cA1_1, sA, 0);
    STAGE2(gB1_0, cB1_0, gB1_1, cB1_1, sB, 0);
    STAGE2(gB2_0, cB2_0, gB2_1, cB2_1, sB, 0);
    STAGE2(gA2_0, cA2_0, gA2_1, cA2_1, sA, 0);

    const int nt = K >> 6;
    for (int tt = 0; tt < nt - 1; ++tt) {
        const int sl = tt & 1;
        short8 aF[2][4], b0F[2][2], b1F[2][2];
        // P1: A[mq0] x B[nq0]
        VMW(4);                                  // A1,B1(tt) complete
        __builtin_amdgcn_s_barrier();
        READ_A(aF, 0, sl);
        READ_B(b0F, 0, sl);
        STAGE2(gA1_0, cA1_0, gA1_1, cA1_1, sA, tt + 1);
        MFMA16(aF, b0F, 0, 0);
        // P2: A[mq0] x B[nq1]  (A regs reused)
        VMW(4);                                  // B2(tt) complete
        __builtin_amdgcn_s_barrier();
        READ_B(b1F, 1, sl);
        STAGE2(gB1_0, cB1_0, gB1_1, cB1_1, sB, tt + 1);
        MFMA16(aF, b1F, 0, 2);
        // P3: A[mq1] x B[nq1]  (B1 regs reused)
        VMW(4);                                  // A2(tt) complete
        __builtin_amdgcn_s_barrier();
        READ_A(aF, 1, sl);
        STAGE2(gB2_0, cB2_0, gB2_1, cB2_1, sB, tt + 1);
        MFMA16(aF, b1F, 4, 2);
        // P4: A[mq1] x B[nq0]  (both reused, no reads, no barrier)
        STAGE2(gA2_0, cA2_0, gA2_1, cA2_1, sA, tt + 1);
        MFMA16(aF, b0F, 4, 0);
    }
    {   // ---- final tile (no staging): drain 4 -> 2 -> 0 ----
        const int sl = (nt - 1) & 1;
        short8 aF[2][4], b0F[2][2], b1F[2][2];
        VMW(4);
        __builtin_amdgcn_s_barrier();
        READ_A(aF, 0, sl);
        READ_B(b0F, 0, sl);
        MFMA16(aF, b0F, 0, 0);
        VMW(2);
        __builtin_amdgcn_s_barrier();
        READ_B(b1F, 1, sl);
        MFMA16(aF, b1F, 0, 2);
        VMW(0);
        __builtin_amdgcn_s_barrier();
        READ_A(aF, 1, sl);
        MFMA16(aF, b1F, 4, 2);
        MFMA16(aF, b0F, 4, 0);
    }

    // ---- epilogue: C/D layout col = l&15, row = (l>>4)*4 + r ----
    float bv[4];
    #pragma unroll
    for (int jj = 0; jj < 4; ++jj) bv[jj] = bias[n_blk + wn + jj * 16 + rsel];
    #pragma unroll
    for (int ii = 0; ii < 8; ++ii) {
        const int rbase = m_blk + wm + (ii >> 2) * 64 + (ii & 3) * 16 + quad * 4;
        #pragma unroll
        for (int r = 0; r < 4; ++r) {
            float* cp = C + (size_t)(rbase + r) * N + n_blk + wn + rsel;
            #pragma unroll
            for (int jj = 0; jj < 4; ++jj)
                cp[jj * 16] = acc[ii][jj][r] + bv[jj];
        }
    }
}

extern "C" void kernel_launch(void* const* d_in, const int* in_sizes, int n_in,
                              void* d_out, int out_size, void* d_ws, size_t ws_size,
                              hipStream_t stream) {
    const float* x    = (const float*)d_in[0];
    const float* wgt  = (const float*)d_in[1];
    const float* bias = (const float*)d_in[2];
    float* out = (float*)d_out;

    const int x_size = in_sizes[0];      // 33554432
    const int w_size = in_sizes[1];      // 1048576
    const int N = in_sizes[2];           // 1024 (Dout)
    const int K = w_size / N;            // 1024 (Din)
    const int M = x_size / K;            // 32768

    char* ws = (char*)d_ws;
    unsigned short* qx = (unsigned short*)ws;
    unsigned short* qw = (unsigned short*)(ws + (size_t)M * K * sizeof(unsigned short));
    float* table  = (float*)(ws + (size_t)M * K * 2 + (size_t)N * K * 2);
    float* bounds = table + 32;
    unsigned char* lut = (unsigned char*)(bounds + 32);

    build_table_k<<<1, 32, 0, stream>>>(table, bounds, lut);

    const int n8x = x_size / 8, n8w = w_size / 8;
    const int nblk_x = (n8x + 255) / 256, nblk_w = (n8w + 255) / 256;
    quantize_k<<<nblk_x + nblk_w, 256, 0, stream>>>(
        (const float4*)x, (US8*)qx, nblk_x, n8x,
        (const float4*)wgt, (US8*)qw, n8w, table, bounds, lut);

    const int grid = (M / 256) * (N / 256);   // 512
    gemm_bt_k<<<grid, 512, 0, stream>>>(qx, qw, bias, out, M, N, K);
}

// Round 3
// 296.031 us; speedup vs baseline: 1.0810x; 1.0299x over previous
//
#include <hip/hip_runtime.h>
#include <hip/hip_bf16.h>

typedef __attribute__((ext_vector_type(8))) short short8;
typedef __attribute__((ext_vector_type(4))) float f32x4;

struct alignas(16) US8 { unsigned short s[8]; };

// ---------------- ndtri in double (Acklam + 2 Halley refinements) ----------------
__device__ double ndtri_d(double p) {
    const double a1 = -3.969683028665376e+01, a2 = 2.209460984245205e+02,
                 a3 = -2.759285104469687e+02, a4 = 1.383577518672690e+02,
                 a5 = -3.066479806614716e+01, a6 = 2.506628277459239e+00;
    const double b1 = -5.447609879822406e+01, b2 = 1.615858368580409e+02,
                 b3 = -1.556989798598866e+02, b4 = 6.680131188771972e+01,
                 b5 = -1.328068155288572e+01;
    const double c1 = -7.784894002430293e-03, c2 = -3.223964580411365e-01,
                 c3 = -2.400758277161838e+00, c4 = -2.549732539343734e+00,
                 c5 = 4.374664141464968e+00,  c6 = 2.938163982698783e+00;
    const double d1 = 7.784695709041462e-03, d2 = 3.224671290700398e-01,
                 d3 = 2.445134137142996e+00, d4 = 3.754408661907416e+00;
    const double plow = 0.02425, phigh = 1.0 - 0.02425;
    double x;
    if (p < plow) {
        double q = sqrt(-2.0 * log(p));
        x = (((((c1*q+c2)*q+c3)*q+c4)*q+c5)*q+c6) / ((((d1*q+d2)*q+d3)*q+d4)*q+1.0);
    } else if (p <= phigh) {
        double q = p - 0.5, r = q * q;
        x = (((((a1*r+a2)*r+a3)*r+a4)*r+a5)*r+a6)*q / (((((b1*r+b2)*r+b3)*r+b4)*r+b5)*r+1.0);
    } else {
        double q = sqrt(-2.0 * log(1.0 - p));
        x = -(((((c1*q+c2)*q+c3)*q+c4)*q+c5)*q+c6) / ((((d1*q+d2)*q+d3)*q+d4)*q+1.0);
    }
    #pragma unroll
    for (int it = 0; it < 2; ++it) {
        double e = 0.5 * erfc(-x * 0.70710678118654752440) - p;
        double u = e * 2.50662827463100050242 * exp(0.5 * x * x);
        x = x - u / (1.0 + 0.5 * x * u);
    }
    return x;
}

// table[32], bounds[32] (bounds[31]=+inf), lut[256] bucket->base index
__global__ void build_table_k(float* __restrict__ table, float* __restrict__ bounds,
                              unsigned char* __restrict__ lut) {
    __shared__ float sT[32], sBd[32];
    const int i = threadIdx.x;  // 0..31
    const double OFF = 0.9677083;
    double v;
    if (i == 16) {
        v = 0.0;
    } else if (i < 16) {
        const double a = 1.0 - OFF;
        double p = a + (0.5 - a) * ((double)i / 16.0);
        v = ndtri_d(p) / (-ndtri_d(a));
    } else {
        int j = i - 16;
        double p = 0.5 + (OFF - 0.5) * ((double)j / 15.0);
        v = ndtri_d(p) / ndtri_d(OFF);
    }
    float tv = (float)v;
    sT[i] = tv;
    table[i] = tv;
    __syncthreads();
    float bd;
    if (i < 31) bd = 0.5f * (sT[i] + sT[i + 1]);   // fp32, like reference
    else        bd = __builtin_inff();
    sBd[i] = bd;
    bounds[i] = bd;
    __syncthreads();
    // LUT with margin 2^-20: base[j] = count(bounds < n_j - margin).
    for (int j = i; j < 256; j += 32) {
        float nj = (float)j * (1.0f / 128.0f) - 1.0f - 0x1p-20f;
        int c = 0;
        #pragma unroll
        for (int k = 0; k < 31; ++k) c += (sBd[k] < nj) ? 1 : 0;
        lut[j] = (unsigned char)c;
    }
}

// ---------------- blockwise NF5 quantize: fp32 -> bf16 ----------------
__device__ __forceinline__ unsigned short q_one(float n, float scale,
                                                const float* sT, const float* sBnd,
                                                const unsigned char* sLut) {
    float u = fmaf(n, 0.5f, 0.5f);                 // [0,1]
    int b = (int)(u * 256.0f);
    b = min(b, 255);
    int base = sLut[b];
    int idx = base + ((sBnd[base] < n) ? 1 : 0);   // == count(bounds < n)
    float q = sT[idx] * scale;                     // exact fp32 (pow2 scale)
    __hip_bfloat16 h = __float2bfloat16(q);
    return *reinterpret_cast<unsigned short*>(&h);
}

__global__ __launch_bounds__(256) void quantize_k(const float4* __restrict__ x,
                                                  US8* __restrict__ qx, int nblk_x, int n8x,
                                                  const float4* __restrict__ wgt,
                                                  US8* __restrict__ qw, int n8w,
                                                  const float* __restrict__ table,
                                                  const float* __restrict__ bounds,
                                                  const unsigned char* __restrict__ lut) {
    __shared__ float sT[32], sBnd[32];
    __shared__ unsigned char sLut[256];
    const int tid = threadIdx.x;
    if (tid < 32) { sT[tid] = table[tid]; sBnd[tid] = bounds[tid]; }
    sLut[tid] = lut[tid];
    __syncthreads();
    const float4* in; US8* out; int t, n8;
    if ((int)blockIdx.x < nblk_x) { in = x;   out = qx; t = blockIdx.x * 256 + tid;            n8 = n8x; }
    else                          { in = wgt; out = qw; t = (blockIdx.x - nblk_x) * 256 + tid; n8 = n8w; }
    if (t >= n8) return;
    float4 v0 = in[2 * t];
    float4 v1 = in[2 * t + 1];
    float am = fmaxf(fmaxf(fmaxf(fabsf(v0.x), fabsf(v0.y)), fmaxf(fabsf(v0.z), fabsf(v0.w))),
                     fmaxf(fmaxf(fabsf(v1.x), fabsf(v1.y)), fmaxf(fabsf(v1.z), fabsf(v1.w))));
    am = fmaxf(am, __shfl_xor(am, 1));
    am = fmaxf(am, __shfl_xor(am, 2));
    am = fmaxf(am, 1e-12f);
    int e;
    float m = frexpf(am, &e);                      // am = m * 2^e, m in [0.5,1)
    int se = (m == 0.5f) ? (e - 1) : e;
    float scale = ldexpf(1.0f, se);
    float inv   = ldexpf(1.0f, -se);               // exact reciprocal
    US8 o;
    o.s[0] = q_one(v0.x * inv, scale, sT, sBnd, sLut);
    o.s[1] = q_one(v0.y * inv, scale, sT, sBnd, sLut);
    o.s[2] = q_one(v0.z * inv, scale, sT, sBnd, sLut);
    o.s[3] = q_one(v0.w * inv, scale, sT, sBnd, sLut);
    o.s[4] = q_one(v1.x * inv, scale, sT, sBnd, sLut);
    o.s[5] = q_one(v1.y * inv, scale, sT, sBnd, sLut);
    o.s[6] = q_one(v1.z * inv, scale, sT, sBnd, sLut);
    o.s[7] = q_one(v1.w * inv, scale, sT, sBnd, sLut);
    out[t] = o;
}

// ---------------- bf16 MFMA GEMM, 256x256 tile, 8 waves, look-ahead pipeline ----
// C[M,N] = A[M,K] * B[N,K]^T + bias.
// LDS layout (per 64-k tile, per matrix): 32 chunks of [8 rows][8 octets], XOR swizzle:
// within a chunk, 16B slot (r8,u) holds k-octet u^r8 of row r8. gload_lds writes lane l
// at slot l; global source octet (l&7)^(l>>3). Fragment read at fixed k8 hits all 8
// bank-quads across r8 -> conflict-free (measured 0).
//
// Phases are (mq, ks) so each phase's MFMA is A-buf x B-buf of ONE k-slot, and every
// phase's operands are ds_read ONE PHASE EARLY (under the previous MFMA cluster):
//   P1 (0,0): JIT read A(0,0),B(0) + ahead A(0,1),B(1) ; stage B1' ; MFMA Ab0 x Bb0
//   P2 (0,1): ahead A(1,1)->Ab0                        ; stage B2' ; MFMA Ab1 x Bb1
//   P3 (1,1): ahead A(1,0)->Ab1 (no sync needed)       ; stage A1' ; MFMA Ab0 x Bb1
//   P4 (1,0): no reads (no sync)                       ; stage A2' ; MFMA Ab1 x Bb0
// Buffer rotation is fully static (period = 1 tile); frag regs = 64 VGPR (same as
// before) -- critical: acc holds 128 AGPRs, and 2 waves/SIMD needs total <= 256.
// Ledger (2 gloads per group, stage order B1,B2,A1,A2):
//   P1 entry outstanding 8 {B1,B2,A1,A2}(tt): VMW(2) completes B1,B2,A1 (covers the
//   full B tile + A(0,*)); stage B1' -> 4.  P2: VMW(2) completes A2(tt); stage -> 4.
//   P3: A(1,0) already confirmed -> no VMW/barrier; stage -> 6.  P4: stage -> 8.
//   2 barriers/tile, vmcnt never drains to 0 in the main loop. Final tile: 2 -> 0.
__device__ __forceinline__ void gload_lds16(const unsigned short* g, unsigned short* s) {
    __builtin_amdgcn_global_load_lds(
        (const __attribute__((address_space(1))) unsigned int*)g,
        (__attribute__((address_space(3))) unsigned int*)s, 16, 0, 0);
}

#define STAGE2(G0, C0, G1, C1, SM, T1)                                       \
    { const int sl_ = (T1) & 1;                                              \
      gload_lds16((G0) + (size_t)(T1) * 64, &SM[sl_][(C0) * 512]);           \
      gload_lds16((G1) + (size_t)(T1) * 64, &SM[sl_][(C1) * 512]); }

// 4 ds_read_b128: A fragments (rows wm+MQ*64 .. +63) of k-slot KS.
#define READ_A1(DST, MQ, KS, SLOT)                                           \
    {                                                                        \
        const int k8_ = (KS) * 4 + quad;                                     \
        _Pragma("unroll")                                                    \
        for (int i = 0; i < 4; ++i) {                                        \
            const int ra = wm + (MQ) * 64 + i * 16 + rsel;                   \
            DST[i] = *(const short8*)&sA[SLOT][                              \
                ((ra >> 3) * 64 + (ra & 7) * 8 + ((k8_ ^ ra) & 7)) * 8];     \
        }                                                                    \
    }

// 4 ds_read_b128: B fragments (rows wn .. wn+63) of k-slot KS.
#define READ_B1(DST, KS, SLOT)                                               \
    {                                                                        \
        const int k8_ = (KS) * 4 + quad;                                     \
        _Pragma("unroll")                                                    \
        for (int j = 0; j < 4; ++j) {                                        \
            const int rb = wn + j * 16 + rsel;                               \
            DST[j] = *(const short8*)&sB[SLOT][                              \
                ((rb >> 3) * 64 + (rb & 7) * 8 + ((k8_ ^ rb) & 7)) * 8];     \
        }                                                                    \
    }

// 16 MFMA: one (mq, ks) phase. acc row = MQ*4+i, col = j.
#define MFMA_PH(AB, BB, MQ)                                                  \
    __builtin_amdgcn_s_setprio(1);                                           \
    _Pragma("unroll")                                                        \
    for (int i = 0; i < 4; ++i)                                              \
        _Pragma("unroll")                                                    \
        for (int j = 0; j < 4; ++j)                                          \
            acc[(MQ) * 4 + i][j] =                                           \
                __builtin_amdgcn_mfma_f32_16x16x32_bf16(                     \
                    AB[i], BB[j], acc[(MQ) * 4 + i][j], 0, 0, 0);            \
    __builtin_amdgcn_s_setprio(0);

#define VMW(N) asm volatile("s_waitcnt vmcnt(" #N ")" ::: "memory")
#define SCHED_FENCE() __builtin_amdgcn_sched_barrier(0)

__global__ __launch_bounds__(512, 1) void gemm_bt_k(const unsigned short* __restrict__ A,
                                                    const unsigned short* __restrict__ B,
                                                    const float* __restrict__ bias,
                                                    float* __restrict__ C,
                                                    int M, int N, int K) {
    __shared__ unsigned short sA[2][256 * 64];   // 64 KiB
    __shared__ unsigned short sB[2][256 * 64];   // 64 KiB
    const int t = threadIdx.x;
    const int w = t >> 6, l = t & 63;

    // XCD-aware swizzle: contiguous gid chunk per XCD, n fastest (A-panel L2 reuse).
    const int nB = N >> 8, mB = M >> 8;
    int m_idx, n_idx;
    {
        const unsigned int lin = blockIdx.x;
        const unsigned int nwg = (unsigned int)(nB * mB);
        unsigned int gid = lin;
        if ((nwg & 7u) == 0u) {
            const unsigned int per = nwg >> 3;
            gid = (lin & 7u) * per + (lin >> 3);
        }
        n_idx = (int)(gid % (unsigned int)nB);
        m_idx = (int)(gid / (unsigned int)nB);
    }
    const int m_blk = m_idx << 8, n_blk = n_idx << 8;
    const int wm = (w >> 2) * 128;          // wave A-row base (2 waves in M)
    const int wn = (w & 3) * 64;            // wave B-row base (4 waves in N)
    const int rsel = l & 15, quad = l >> 4;

    // ---- staging geometry (per wave: 2 chunks per group) ----
    const int st_row = l >> 3;
    const int st_oct = (l & 7) ^ st_row;
    const int ja0 = 2 * w, ja1 = 2 * w + 1;
    const int cA1_0 = (ja0 < 8) ? ja0 : ja0 + 8;          // A1: chunks {0-7,16-23}
    const int cA1_1 = (ja1 < 8) ? ja1 : ja1 + 8;
    const int cA2_0 = cA1_0 + 8, cA2_1 = cA1_1 + 8;       // A2: chunks {8-15,24-31}
    const int cB1_0 = (ja0 & 3) + (ja0 >> 2) * 8;         // B1: chunks {0-3,8-11,16-19,24-27}
    const int cB1_1 = (ja1 & 3) + (ja1 >> 2) * 8;
    const int cB2_0 = cB1_0 + 4, cB2_1 = cB1_1 + 4;       // B2: +4

    const unsigned short* gA1_0 = A + (size_t)(m_blk + cA1_0 * 8 + st_row) * K + st_oct * 8;
    const unsigned short* gA1_1 = A + (size_t)(m_blk + cA1_1 * 8 + st_row) * K + st_oct * 8;
    const unsigned short* gA2_0 = A + (size_t)(m_blk + cA2_0 * 8 + st_row) * K + st_oct * 8;
    const unsigned short* gA2_1 = A + (size_t)(m_blk + cA2_1 * 8 + st_row) * K + st_oct * 8;
    const unsigned short* gB1_0 = B + (size_t)(n_blk + cB1_0 * 8 + st_row) * K + st_oct * 8;
    const unsigned short* gB1_1 = B + (size_t)(n_blk + cB1_1 * 8 + st_row) * K + st_oct * 8;
    const unsigned short* gB2_0 = B + (size_t)(n_blk + cB2_0 * 8 + st_row) * K + st_oct * 8;
    const unsigned short* gB2_1 = B + (size_t)(n_blk + cB2_1 * 8 + st_row) * K + st_oct * 8;

    f32x4 acc[8][4];
    #pragma unroll
    for (int i = 0; i < 8; ++i)
        #pragma unroll
        for (int j = 0; j < 4; ++j)
            acc[i][j] = (f32x4){0.f, 0.f, 0.f, 0.f};

    // ---- prologue: stage tile 0 in group order B1, B2, A1, A2 ----
    STAGE2(gB1_0, cB1_0, gB1_1, cB1_1, sB, 0);
    STAGE2(gB2_0, cB2_0, gB2_1, cB2_1, sB, 0);
    STAGE2(gA1_0, cA1_0, gA1_1, cA1_1, sA, 0);
    STAGE2(gA2_0, cA2_0, gA2_1, cA2_1, sA, 0);

    short8 Ab0[4], Ab1[4], Bb0[4], Bb1[4];

    const int nt = K >> 6;
    for (int tt = 0; tt < nt - 1; ++tt) {
        const int sl = tt & 1;
        // P1 (mq0,ks0): JIT A(0,0),B(0); ahead A(0,1),B(1)
        VMW(2);                               // B1,B2,A1(tt) complete
        __builtin_amdgcn_s_barrier();
        READ_A1(Ab0, 0, 0, sl);
        READ_B1(Bb0, 0, sl);
        READ_A1(Ab1, 0, 1, sl);
        READ_B1(Bb1, 1, sl);
        STAGE2(gB1_0, cB1_0, gB1_1, cB1_1, sB, tt + 1);
        SCHED_FENCE();
        MFMA_PH(Ab0, Bb0, 0);
        // P2 (mq0,ks1): ahead A(1,1) -> Ab0
        VMW(2);                               // A2(tt) complete
        __builtin_amdgcn_s_barrier();
        READ_A1(Ab0, 1, 1, sl);
        STAGE2(gB2_0, cB2_0, gB2_1, cB2_1, sB, tt + 1);
        SCHED_FENCE();
        MFMA_PH(Ab1, Bb1, 0);
        // P3 (mq1,ks1): ahead A(1,0) -> Ab1 (A2 chunks already confirmed; no sync)
        READ_A1(Ab1, 1, 0, sl);
        STAGE2(gA1_0, cA1_0, gA1_1, cA1_1, sA, tt + 1);
        SCHED_FENCE();
        MFMA_PH(Ab0, Bb1, 1);
        // P4 (mq1,ks0): no reads
        STAGE2(gA2_0, cA2_0, gA2_1, cA2_1, sA, tt + 1);
        SCHED_FENCE();
        MFMA_PH(Ab1, Bb0, 1);
    }
    {   // ---- final tile (no staging): drain 2 -> 0 ----
        const int sl = (nt - 1) & 1;
        VMW(2);
        __builtin_amdgcn_s_barrier();
        READ_A1(Ab0, 0, 0, sl);
        READ_B1(Bb0, 0, sl);
        READ_A1(Ab1, 0, 1, sl);
        READ_B1(Bb1, 1, sl);
        SCHED_FENCE();
        MFMA_PH(Ab0, Bb0, 0);
        VMW(0);
        __builtin_amdgcn_s_barrier();
        READ_A1(Ab0, 1, 1, sl);
        SCHED_FENCE();
        MFMA_PH(Ab1, Bb1, 0);
        READ_A1(Ab1, 1, 0, sl);
        SCHED_FENCE();
        MFMA_PH(Ab0, Bb1, 1);
        MFMA_PH(Ab1, Bb0, 1);
    }

    // ---- epilogue: C/D layout col = l&15, row = (l>>4)*4 + r ----
    float bv[4];
    #pragma unroll
    for (int jj = 0; jj < 4; ++jj) bv[jj] = bias[n_blk + wn + jj * 16 + rsel];
    #pragma unroll
    for (int ii = 0; ii < 8; ++ii) {
        const int rbase = m_blk + wm + (ii >> 2) * 64 + (ii & 3) * 16 + quad * 4;
        #pragma unroll
        for (int r = 0; r < 4; ++r) {
            float* cp = C + (size_t)(rbase + r) * N + n_blk + wn + rsel;
            #pragma unroll
            for (int jj = 0; jj < 4; ++jj)
                cp[jj * 16] = acc[ii][jj][r] + bv[jj];
        }
    }
}

extern "C" void kernel_launch(void* const* d_in, const int* in_sizes, int n_in,
                              void* d_out, int out_size, void* d_ws, size_t ws_size,
                              hipStream_t stream) {
    const float* x    = (const float*)d_in[0];
    const float* wgt  = (const float*)d_in[1];
    const float* bias = (const float*)d_in[2];
    float* out = (float*)d_out;

    const int x_size = in_sizes[0];      // 33554432
    const int w_size = in_sizes[1];      // 1048576
    const int N = in_sizes[2];           // 1024 (Dout)
    const int K = w_size / N;            // 1024 (Din)
    const int M = x_size / K;            // 32768

    char* ws = (char*)d_ws;
    unsigned short* qx = (unsigned short*)ws;
    unsigned short* qw = (unsigned short*)(ws + (size_t)M * K * sizeof(unsigned short));
    float* table  = (float*)(ws + (size_t)M * K * 2 + (size_t)N * K * 2);
    float* bounds = table + 32;
    unsigned char* lut = (unsigned char*)(bounds + 32);

    build_table_k<<<1, 32, 0, stream>>>(table, bounds, lut);

    const int n8x = x_size / 8, n8w = w_size / 8;
    const int nblk_x = (n8x + 255) / 256, nblk_w = (n8w + 255) / 256;
    quantize_k<<<nblk_x + nblk_w, 256, 0, stream>>>(
        (const float4*)x, (US8*)qx, nblk_x, n8x,
        (const float4*)wgt, (US8*)qw, n8w, table, bounds, lut);

    const int grid = (M / 256) * (N / 256);   // 512
    gemm_bt_k<<<grid, 512, 0, stream>>>(qx, qw, bias, out, M, N, K);
}